// Round 10
// baseline (732.337 us; speedup 1.0000x reference)
//
#include <hip/hip_runtime.h>
#include <hip/hip_bf16.h>
#include <hip/hip_cooperative_groups.h>

namespace cg = cooperative_groups;

#define HW   4096
#define NBLK 768

typedef __bf16 bf_t;
typedef __bf16 bf8_t __attribute__((ext_vector_type(8)));
typedef __bf16 bf4v_t __attribute__((ext_vector_type(4)));
typedef float  f4_t  __attribute__((ext_vector_type(4)));

// Static device workspace (element offsets into g_ws, in floats):
#define OFF_A    0              // 2*50*HW NCHW offset maps
#define OFF_B    409600         // 2*98*HW
#define A1_F32   1212416        // NHWC fp32 [b][4096][64] = 524288 each
#define B1_F32   1736704
#define A2_F32   2260992
#define B2_F32   2785280
#define XA_F32   3309568
#define XB_F32   3833856
#define XA_HI    4358144        // bf16 NHWC = 262144 floats each
#define XA_LO    4620288
#define XB_HI    4882432
#define XB_LO    5144576
#define A1_HI    5406720
#define A1_LO    5668864
#define B1_HI    5931008
#define B1_LO    6193152
#define AW_A1    6455296        // conv weight packs (bf16 A-frag)
#define AW_B1    6464512
#define AW_A2    6515712
#define AW_B2    6566912
#define DW_A1    6767616        // depthwise weights transposed [KK][64]
#define DW_B1    6768192
#define DW_A2    6769792
#define DW_B2    6771392
#define WS_TOT   6774528

__device__ __align__(16) float g_ws[WS_TOT];

__device__ __forceinline__ bf8_t bf8_zero() {
    bf8_t v;
#pragma unroll
    for (int j = 0; j < 8; ++j) v[j] = (bf_t)0.f;
    return v;
}

// ---------------------------------------------------------------------------
// Weight prep helpers (range-dispatched).
// ---------------------------------------------------------------------------
__device__ __forceinline__ void prep_wA_dev(const float* wg, int aw_off,
                                            int Cout, int K, int NCOT, int lb) {
    const int KK = K * K;
    const int total = KK * NCOT * 128;
    const int idx = lb * 256 + threadIdx.x;
    if (idx >= total) return;
    bf_t* aw = (bf_t*)(g_ws + aw_off);
    int lane = idx & 63;
    int kh   = (idx >> 6) & 1;
    int cot  = (idx >> 7) % NCOT;
    int tap  = idx / (128 * NCOT);
    int co   = cot * 16 + (lane & 15);
    int ci0  = kh * 32 + (lane >> 4) * 8;
    bf8_t v;
#pragma unroll
    for (int j = 0; j < 8; ++j) {
        float f = (co < Cout) ? wg[(co * 64 + ci0 + j) * KK + tap] : 0.f;
        v[j] = (bf_t)f;
    }
    *(bf8_t*)&aw[(long)idx * 8] = v;
}

__device__ __forceinline__ void prep_dwT_dev(const float* w, int dst_off,
                                             int KK, int lb) {
    const int idx = lb * 256 + threadIdx.x;
    if (idx < KK * 64) {
        int c = idx & 63, kk = idx >> 6;
        g_ws[dst_off + kk * 64 + c] = w[c * KK + kk];
    }
}

// ---------------------------------------------------------------------------
// Phase 0 body: all weight prep (vb 0..334) + x -> NHWC fp32 / bf16 hi-lo
// split (vb 335..1358). lds = 16*68 floats of shared mem.
// ---------------------------------------------------------------------------
__device__ __forceinline__ void prep_dev(int bi, float* lds,
    const float* __restrict__ x,
    const float* cv0_off_w, const float* c0_off_w,
    const float* cvs_off_w, const float* cs_off_w,
    const float* cv0_w, const float* c0_w,
    const float* cvs_w, const float* cs_w)
{
    if (bi < 335) {
        if      (bi < 9)   prep_wA_dev(cv0_off_w, AW_A1, 18, 3, 2, bi);
        else if (bi < 59)  prep_wA_dev(c0_off_w,  AW_B1, 50, 5, 4, bi - 9);
        else if (bi < 109) prep_wA_dev(cvs_off_w, AW_A2, 50, 5, 4, bi - 59);
        else if (bi < 305) prep_wA_dev(cs_off_w,  AW_B2, 98, 7, 8, bi - 109);
        else if (bi < 308) prep_dwT_dev(cv0_w, DW_A1, 9,  bi - 305);
        else if (bi < 315) prep_dwT_dev(c0_w,  DW_B1, 25, bi - 308);
        else if (bi < 322) prep_dwT_dev(cvs_w, DW_A2, 25, bi - 315);
        else               prep_dwT_dev(cs_w,  DW_B2, 49, bi - 322);
        return;
    }
    const int s  = bi - 335;
    const int b  = s & 1;
    const int br = (s >> 1) & 1;
    const int p0 = (s >> 2) * 16;
    const float* sb = x + (long)b * (128 * HW) + (long)br * (64 * HW);
    bf_t*  dhi = (bf_t*)(g_ws + (br ? XB_HI : XA_HI));
    bf_t*  dlo = (bf_t*)(g_ws + (br ? XB_LO : XA_LO));
    float* df  = g_ws + (br ? XB_F32 : XA_F32);
    const int t = threadIdx.x;
    {
        const int px = t & 15;
        const int c0 = t >> 4;
#pragma unroll
        for (int pass = 0; pass < 4; ++pass) {
            int ci = c0 + pass * 16;
            lds[px * 68 + ci] = sb[ci * HW + p0 + px];
        }
    }
    __syncthreads();
    if (t < 128) {
        int px = t >> 3, q = t & 7;
        bf8_t vh, vl;
        f4_t  f0, f1;
#pragma unroll
        for (int j = 0; j < 8; ++j) {
            float a = lds[px * 68 + q * 8 + j];
            bf_t hcast = (bf_t)a;
            vh[j] = hcast;
            vl[j] = (bf_t)(a - (float)hcast);
            if (j < 4) f0[j] = a; else f1[j - 4] = a;
        }
        long base = (((long)b * 4096 + p0 + px) * 64) + q * 8;
        *(bf8_t*)&dhi[base] = vh;
        *(bf8_t*)&dlo[base] = vl;
        *(f4_t*)&df[base]     = f0;
        *(f4_t*)&df[base + 4] = f1;
    }
}

// ---------------------------------------------------------------------------
// MFMA implicit-GEMM conv body (hi/lo split input).
// ---------------------------------------------------------------------------
template<int K, int DIL, int PAD, int NCOT, int CPG>
__device__ __forceinline__ void mfma_conv_dev(
    int bx, int by, bf_t* smem,
    int hi_off, int lo_off, int aw_off, const float* __restrict__ bias,
    int dst_off, int Cout)
{
    constexpr int COLS = 64 + 2 * PAD;
    const bf_t* shi = (const bf_t*)(g_ws + hi_off);
    const bf_t* slo = (const bf_t*)(g_ws + lo_off);
    const bf_t* aw  = (const bf_t*)(g_ws + aw_off);
    float* dst = g_ws + dst_off;
    bf_t* lds0 = smem;
    bf_t* lds1 = smem + COLS * 72;

    const int t    = threadIdx.x;
    const int lane = t & 63;
    const int wv   = t >> 6;
    const int b    = bx >> 6;
    const int h    = bx & 63;
    const int ct0  = by * CPG;

    const int n0 = lane & 15;
    const int kq = lane >> 4;

    f4_t acc[CPG];
#pragma unroll
    for (int i = 0; i < CPG; ++i) acc[i] = (f4_t){0.f, 0.f, 0.f, 0.f};

    for (int ky = 0; ky < K; ++ky) {
        const int ih = h - PAD + ky * DIL;
        __syncthreads();
        if ((unsigned)ih < 64u) {
            const long rowb = ((long)b * 4096 + ih * 64) * 64;
            for (int c = t; c < COLS * 8; c += 256) {
                int col = c >> 3, q = c & 7;
                int iw = col - PAD;
                bf8_t vh, vl;
                if ((unsigned)iw < 64u) {
                    vh = *(const bf8_t*)&shi[rowb + iw * 64 + q * 8];
                    vl = *(const bf8_t*)&slo[rowb + iw * 64 + q * 8];
                } else { vh = bf8_zero(); vl = bf8_zero(); }
                *(bf8_t*)&lds0[col * 72 + q * 8] = vh;
                *(bf8_t*)&lds1[col * 72 + q * 8] = vl;
            }
        } else {
            bf8_t z = bf8_zero();
            for (int c = t; c < COLS * 8; c += 256) {
                int col = c >> 3, q = c & 7;
                *(bf8_t*)&lds0[col * 72 + q * 8] = z;
                *(bf8_t*)&lds1[col * 72 + q * 8] = z;
            }
        }
        __syncthreads();
#pragma unroll
        for (int kx = 0; kx < K; ++kx) {
            const int tap = ky * K + kx;
            bf8_t afr[CPG][2];
#pragma unroll
            for (int ct = 0; ct < CPG; ++ct)
#pragma unroll
                for (int kh = 0; kh < 2; ++kh)
                    afr[ct][kh] = *(const bf8_t*)
                        &aw[((((long)tap * NCOT + ct0 + ct) * 2 + kh) * 64 + lane) * 8];
            const int colb = (wv * 16 + n0 + kx * DIL) * 72;
#pragma unroll
            for (int kh = 0; kh < 2; ++kh) {
                const bf8_t bh = *(const bf8_t*)&lds0[colb + kh * 32 + kq * 8];
                const bf8_t bl = *(const bf8_t*)&lds1[colb + kh * 32 + kq * 8];
#pragma unroll
                for (int ct = 0; ct < CPG; ++ct) {
                    acc[ct] = __builtin_amdgcn_mfma_f32_16x16x32_bf16(
                        afr[ct][kh], bh, acc[ct], 0, 0, 0);
                    acc[ct] = __builtin_amdgcn_mfma_f32_16x16x32_bf16(
                        afr[ct][kh], bl, acc[ct], 0, 0, 0);
                }
            }
        }
    }

    const int w = wv * 16 + n0;
#pragma unroll
    for (int ct = 0; ct < CPG; ++ct) {
#pragma unroll
        for (int r = 0; r < 4; ++r) {
            int co = (ct0 + ct) * 16 + kq * 4 + r;
            if (co < Cout)
                dst[((long)b * Cout + co) * HW + h * 64 + w] = acc[ct][r] + bias[co];
        }
    }
}

// ---------------------------------------------------------------------------
// Fused deformable sampler (R6 single-dwordx4-gather + R7 store-split).
// recs/dwl are caller-provided LDS regions; dwl must be written (or being
// written) by the caller before this function's internal barrier.
// ---------------------------------------------------------------------------
template<int KK, int WRITE_HILO>
__device__ __forceinline__ void sample_fused_dev(
    int s, float* recs, float* dwl, int src_off, int off_off,
    int dst_off, int hi_off, int lo_off, int K, int pad, int dil)
{
    const int t   = threadIdx.x;
    const int pgi = ((s & 7) << 7) | (s >> 3);   // XCD-contiguous chunks

    // phase A: pair records for this block's 8 pixels
    for (int rec = t; rec < 8 * KK; rec += 256) {
        const int pxl = rec & 7;
        const int kk  = rec >> 3;
        const int pg  = pgi * 8 + pxl;
        const int b   = pg >> 12;
        const int p   = pg & 4095;
        const int h   = p >> 6, w = p & 63;
        const float oy = g_ws[off_off + ((long)(b * 2 * KK + 2 * kk)) * HW + p];
        const float ox = g_ws[off_off + ((long)(b * 2 * KK + 2 * kk + 1)) * HW + p];
        const float py = oy + (float)(h - pad + (kk / K) * dil);
        const float px = ox + (float)(w - pad + (kk % K) * dil);
        const float fy = floorf(py), fx = floorf(px);
        const float ly = py - fy,    lx = px - fx;
        const int y0 = (int)fy, x0 = (int)fx;
        const int y1 = y0 + 1,  x1 = x0 + 1;
        const float ry0 = ((unsigned)y0 < 64u) ? (1.f - ly) : 0.f;
        const float ry1 = ((unsigned)y1 < 64u) ? ly : 0.f;
        const float cx0 = ((unsigned)x0 < 64u) ? (1.f - lx) : 0.f;
        const float cx1 = ((unsigned)x1 < 64u) ? lx : 0.f;
        const int xbase = min(max(x0, 0), 62);
        const float sA = (xbase == x0) ? cx0 : ((xbase == x1) ? cx1 : 0.f);
        const float sB = ((xbase + 1) == x1) ? cx1
                                             : (((xbase + 1) == x0) ? cx0 : 0.f);
        const int y0c = min(max(y0, 0), 63), y1c = min(max(y1, 0), 63);
        const int a0 = (y0c * 64 + xbase) * 256;   // byte address of row-y0 pair
        const int a1 = (y1c * 64 + xbase) * 256;
        float* rp = &recs[rec * 8];
        f4_t r0, r1;
        r0[0] = ry0 * sA; r0[1] = ry0 * sB;
        r0[2] = __int_as_float(a0); r0[3] = 0.f;
        r1[0] = ry1 * sA; r1[1] = ry1 * sB;
        r1[2] = __int_as_float(a1); r1[3] = 0.f;
        *(f4_t*)rp       = r0;
        *(f4_t*)(rp + 4) = r1;
    }
    __syncthreads();

    // phase B: wave wv handles pixels {2wv, 2wv+1}
    const int lane = t & 63;
    const int half = (lane >> 5) & 1;  // row select
    const int sub  = (lane >> 4) & 1;  // col slot within the pair
    const int q    = lane & 15;        // channel quad (ch 4q..4q+3)
    const int wv   = t >> 6;
    const int px0  = wv * 2, px1 = wv * 2 + 1;
    const int pg0  = pgi * 8 + px0;
    const int b    = pg0 >> 12;        // both pixels share the batch (8-aligned)

    const char*  sbl = (const char*)(g_ws + src_off + ((long)b << 18))
                       + sub * 256 + q * 16;
    const float* dwp = dwl + q * 4;

    f4_t acc0 = {0.f, 0.f, 0.f, 0.f};
    f4_t acc1 = {0.f, 0.f, 0.f, 0.f};
#pragma unroll
    for (int kk = 0; kk < KK; ++kk) {
        const f4_t r0 = *(const f4_t*)&recs[(kk * 8 + px0) * 8 + half * 4];
        const f4_t r1 = *(const f4_t*)&recs[(kk * 8 + px1) * 8 + half * 4];
        const f4_t dw = *(const f4_t*)(dwp + kk * 64);
        const float w0 = sub ? r0[1] : r0[0];
        const float w1 = sub ? r1[1] : r1[0];
        const f4_t v0 = *(const f4_t*)(sbl + __float_as_int(r0[2]));
        const f4_t v1 = *(const f4_t*)(sbl + __float_as_int(r1[2]));
#pragma unroll
        for (int c = 0; c < 4; ++c) {
            acc0[c] = fmaf(dw[c] * w0, v0[c], acc0[c]);
            acc1[c] = fmaf(dw[c] * w1, v1[c], acc1[c]);
        }
    }

    // combine col slots (xor 16) then rows (xor 32); all lanes end duplicated
#pragma unroll
    for (int c = 0; c < 4; ++c) {
        acc0[c] += __shfl_xor(acc0[c], 16);
        acc0[c] += __shfl_xor(acc0[c], 32);
        acc1[c] += __shfl_xor(acc1[c], 16);
        acc1[c] += __shfl_xor(acc1[c], 32);
    }

    // store epilogue: split across lane groups (all hold the full sums)
    const int p0 = pg0 & 4095;
    const long ob0 = ((long)b * 4096 + p0) * 64 + q * 4;
    const long ob1 = ob0 + 64;                 // px1 = px0 + 1 (same batch)
    const int grp = lane >> 4;
    if (WRITE_HILO) {
        if (grp == 0) {
            *(f4_t*)&g_ws[dst_off + ob0] = acc0;
        } else if (grp == 1) {
            *(f4_t*)&g_ws[dst_off + ob1] = acc1;
        } else if (grp == 2) {
            bf4v_t h0, l0;
#pragma unroll
            for (int c = 0; c < 4; ++c) {
                bf_t hh = (bf_t)acc0[c];
                h0[c] = hh; l0[c] = (bf_t)(acc0[c] - (float)hh);
            }
            *(bf4v_t*)&((bf_t*)(g_ws + hi_off))[ob0] = h0;
            *(bf4v_t*)&((bf_t*)(g_ws + lo_off))[ob0] = l0;
        } else {
            bf4v_t h1, l1;
#pragma unroll
            for (int c = 0; c < 4; ++c) {
                bf_t hh = (bf_t)acc1[c];
                h1[c] = hh; l1[c] = (bf_t)(acc1[c] - (float)hh);
            }
            *(bf4v_t*)&((bf_t*)(g_ws + hi_off))[ob1] = h1;
            *(bf4v_t*)&((bf_t*)(g_ws + lo_off))[ob1] = l1;
        }
    } else {
        if (grp == 0)      *(f4_t*)&g_ws[dst_off + ob0] = acc0;
        else if (grp == 1) *(f4_t*)&g_ws[dst_off + ob1] = acc1;
    }
}

// Per-branch sampler phase (mega): branch fixed per block (bid parity), dwl
// loaded once, s grid-strides over the branch's 1024 units.
template<int KK, int WRITE_HILO>
__device__ __forceinline__ void sample_phase(int g, float* recs, float* dwl,
    int src_off, int off_off, int dwt_off, int dst_off, int hi_off, int lo_off,
    int K, int pad, int dil)
{
    const int t = threadIdx.x;
    for (int e = t; e < KK * 64; e += 256) dwl[e] = g_ws[dwt_off + e];
    for (int s = g; s < 1024; s += NBLK / 2) {
        __syncthreads();   // dwl ready / recs reusable
        sample_fused_dev<KK, WRITE_HILO>(s, recs, dwl, src_off, off_off,
                                         dst_off, hi_off, lo_off, K, pad, dil);
    }
}

// ---------------------------------------------------------------------------
// Phase 5 body: per-branch 1x1 conv (+bias), then out = x * result.
// vb in [0,512): tile = vb&63, by = (vb>>6)&3, b = vb>>8.
// atile = 64*65 floats, wlds = 64*32 floats of shared mem.
// ---------------------------------------------------------------------------
__device__ __forceinline__ void final_dev(int vb, float* atile, float* wlds,
    const float* __restrict__ x,
    const float* __restrict__ w1, const float* __restrict__ b1,
    const float* __restrict__ w2, const float* __restrict__ b2,
    float* __restrict__ out)
{
    const int t  = threadIdx.x;
    const int p0 = (vb & 63) * 64;
    const int by = (vb >> 6) & 3;
    const int b  = vb >> 8;
    const bool brB  = (by >> 1) != 0;
    const int  cbase = (by & 1) * 32;
    const float* a  = g_ws + (brB ? B2_F32 : A2_F32) + (long)b * (4096 * 64);
    const float* wg = brB ? w2 : w1;
    const float* bg = brB ? b2 : b1;

    {
        const int ci = t & 63;
        const int pxg = (t >> 6) * 16;
#pragma unroll
        for (int i = 0; i < 16; ++i) {
            int px = pxg + i;
            atile[px * 65 + ci] = a[(long)(p0 + px) * 64 + ci];
        }
    }
    for (int e = t; e < 2048; e += 256) {
        int col = e & 31, ci = e >> 5;
        wlds[ci * 32 + col] = wg[(cbase + col) * 64 + ci];
    }
    __syncthreads();

    const int px  = t & 63;
    const int cog = t >> 6;
    float acc[8] = {0, 0, 0, 0, 0, 0, 0, 0};
    for (int ci = 0; ci < 64; ++ci) {
        const float av = atile[px * 65 + ci];
        const float* wr = &wlds[ci * 32 + cog * 8];
#pragma unroll
        for (int j = 0; j < 8; ++j) acc[j] = fmaf(av, wr[j], acc[j]);
    }

    const int p = p0 + px;
#pragma unroll
    for (int j = 0; j < 8; ++j) {
        const int co = cbase + cog * 8 + j;
        const int cg = (brB ? 64 : 0) + co;
        const long o = ((long)b * 128 + cg) * HW + p;
        out[o] = (acc[j] + bg[co]) * x[o];
    }
}

// ---------------------------------------------------------------------------
// Mega kernel: all 6 phases, 768 blocks, 5 grid syncs via cooperative groups.
// Launched ONLY via hipLaunchCooperativeKernel (runtime guarantees all 768
// blocks co-resident, else the launch errors and the host falls back).
// __launch_bounds__(256,3): 3 blocks/CU capacity (LDS 25088 -> 6/CU; VGPR
// capped ~168 by the bound).
// ---------------------------------------------------------------------------
__global__ __launch_bounds__(256, 3) void mega_kernel(
    const float* __restrict__ x,
    const float* cv0_off_w, const float* c0_off_w,
    const float* cvs_off_w, const float* cs_off_w,
    const float* cv0_w, const float* c0_w,
    const float* cvs_w, const float* cs_w,
    const float* cv0_off_b, const float* c0_off_b,
    const float* cvs_off_b, const float* cs_off_b,
    const float* conv1_w, const float* conv1_b,
    const float* conv2_w, const float* conv2_b,
    float* __restrict__ out)
{
    extern __shared__ __align__(16) char dsm[];
    float* fsm = (float*)dsm;
    bf_t*  bsm = (bf_t*)dsm;
    const int bid = blockIdx.x;
    cg::grid_group grid = cg::this_grid();

    // ---- P0: weight prep + x NHWC/hi-lo split (1359 vb) ----
    for (int vb = bid; vb < 1359; vb += NBLK) {
        __syncthreads();
        prep_dev(vb, fsm, x, cv0_off_w, c0_off_w, cvs_off_w, cs_off_w,
                 cv0_w, c0_w, cvs_w, cs_w);
    }
    grid.sync();

    // ---- P1: stage-1 offset convs (k3 x256 + k5 x512, CPG1, mod-3) ----
    {
        const int g = bid / 3, r = bid % 3;
        if (r == 0)
            mfma_conv_dev<3, 1, 1, 2, 1>(g & 127, g >> 7, bsm,
                                         XA_HI, XA_LO, AW_A1, cv0_off_b, OFF_A, 18);
        else {
            const int s = 2 * g + (r - 1);
            mfma_conv_dev<5, 1, 2, 4, 1>(s & 127, s >> 7, bsm,
                                         XB_HI, XB_LO, AW_B1, c0_off_b, OFF_B, 50);
        }
    }
    grid.sync();

    // ---- P2: stage-1 sampling (+ hi/lo emit) ----
    if ((bid & 1) == 0)
        sample_phase<9, 1>(bid >> 1, fsm, fsm + 3136,
                           XA_F32, OFF_A, DW_A1, A1_F32, A1_HI, A1_LO, 3, 1, 1);
    else
        sample_phase<25, 1>(bid >> 1, fsm, fsm + 3136,
                            XB_F32, OFF_B, DW_B1, B1_F32, B1_HI, B1_LO, 5, 2, 1);
    grid.sync();

    // ---- P3: stage-2 offset convs (k5 x256 CPG2 + k7 x512 CPG2, mod-3) ----
    {
        const int g = bid / 3, r = bid % 3;
        if (r == 0)
            mfma_conv_dev<5, 3, 6, 4, 2>(g & 127, g >> 7, bsm,
                                         A1_HI, A1_LO, AW_A2, cvs_off_b, OFF_A, 50);
        else {
            const int s = 2 * g + (r - 1);
            mfma_conv_dev<7, 3, 9, 8, 2>(s & 127, s >> 7, bsm,
                                         B1_HI, B1_LO, AW_B2, cs_off_b, OFF_B, 98);
        }
    }
    grid.sync();

    // ---- P4: stage-2 sampling ----
    if ((bid & 1) == 0)
        sample_phase<25, 0>(bid >> 1, fsm, fsm + 3136,
                            A1_F32, OFF_A, DW_A2, A2_F32, 0, 0, 5, 6, 3);
    else
        sample_phase<49, 0>(bid >> 1, fsm, fsm + 3136,
                            B1_F32, OFF_B, DW_B2, B2_F32, 0, 0, 7, 9, 3);
    grid.sync();

    // ---- P5: 1x1 convs + gating multiply (512 vb) ----
    if (bid < 512)
        final_dev(bid, fsm, fsm + 64 * 65, x,
                  conv1_w, conv1_b, conv2_w, conv2_b, out);
}

// ---------------------------------------------------------------------------
// Fallback path: the verified R7 six-kernel pipeline (same device bodies).
// ---------------------------------------------------------------------------
__global__ __launch_bounds__(256) void prep_split_kernel(
    const float* __restrict__ x,
    const float* cv0_off_w, const float* c0_off_w,
    const float* cvs_off_w, const float* cs_off_w,
    const float* cv0_w, const float* c0_w,
    const float* cvs_w, const float* cs_w)
{
    __shared__ float lds[16 * 68];
    prep_dev(blockIdx.x, lds, x, cv0_off_w, c0_off_w, cvs_off_w, cs_off_w,
             cv0_w, c0_w, cvs_w, cs_w);
}

__global__ __launch_bounds__(256) void conv_s1_kernel(
    const float* __restrict__ biasA, const float* __restrict__ biasB)
{
    extern __shared__ __align__(16) bf_t smem1[];
    const int bi = blockIdx.x;
    const int g = bi / 3, r = bi % 3;
    if (r == 0)
        mfma_conv_dev<3, 1, 1, 2, 2>(g & 127, 0, smem1,
                                     XA_HI, XA_LO, AW_A1, biasA, OFF_A, 18);
    else {
        const int s = 2 * g + (r - 1);
        mfma_conv_dev<5, 1, 2, 4, 2>(s & 127, s >> 7, smem1,
                                     XB_HI, XB_LO, AW_B1, biasB, OFF_B, 50);
    }
}

__global__ __launch_bounds__(256) void conv_s2_kernel(
    const float* __restrict__ biasA, const float* __restrict__ biasB)
{
    extern __shared__ __align__(16) bf_t smem2[];
    const int bi = blockIdx.x;
    const int s = bi >> 1;
    if ((bi & 1) == 0)
        mfma_conv_dev<5, 3, 6, 4, 2>(s & 127, s >> 7, smem2,
                                     A1_HI, A1_LO, AW_A2, biasA, OFF_A, 50);
    else
        mfma_conv_dev<7, 3, 9, 8, 4>(s & 127, s >> 7, smem2,
                                     B1_HI, B1_LO, AW_B2, biasB, OFF_B, 98);
}

template<int KK, int WRITE_HILO>
__device__ __forceinline__ void sample_one(int s, float* recs, float* dwl,
    int src_off, int off_off, int dwt_off, int dst_off, int hi_off, int lo_off,
    int K, int pad, int dil)
{
    for (int e = threadIdx.x; e < KK * 64; e += 256) dwl[e] = g_ws[dwt_off + e];
    // sample_fused_dev's internal barrier (after phase A) also covers dwl.
    sample_fused_dev<KK, WRITE_HILO>(s, recs, dwl, src_off, off_off,
                                     dst_off, hi_off, lo_off, K, pad, dil);
}

template<int KA, int KB, int WRITE_HILO>
__global__ __launch_bounds__(256) void sample_kernel(
    int srcA, int offA, int dwtA, int dstA, int hiA, int loA, int padA, int dilA,
    int srcB, int offB, int dwtB, int dstB, int hiB, int loB, int padB, int dilB)
{
    constexpr int KKmax = KB * KB;
    __shared__ __align__(16) float recs[8 * KKmax * 8];
    __shared__ __align__(16) float dwl[KKmax * 64];
    const int bx = blockIdx.x;
    const int s = bx >> 1;
    if ((bx & 1) == 0)
        sample_one<KA * KA, WRITE_HILO>(s, recs, dwl, srcA, offA, dwtA,
                                        dstA, hiA, loA, KA, padA, dilA);
    else
        sample_one<KB * KB, WRITE_HILO>(s, recs, dwl, srcB, offB, dwtB,
                                        dstB, hiB, loB, KB, padB, dilB);
}

// FIXED (R9 bug): launched as 512 one-dimensional blocks; final_dev decodes
// vb = blockIdx.x into (tile, by, b). The R9 version used a 3-D grid but
// ignored blockIdx.y/z, leaving 7/8 of the output unwritten.
__global__ __launch_bounds__(256) void final_kernel(
    const float* __restrict__ x,
    const float* __restrict__ w1, const float* __restrict__ b1,
    const float* __restrict__ w2, const float* __restrict__ b2,
    float* __restrict__ out)
{
    __shared__ float atile[64 * 65];
    __shared__ float wlds[64 * 32];
    final_dev(blockIdx.x, atile, wlds, x, w1, b1, w2, b2, out);
}

// ---------------------------------------------------------------------------
extern "C" void kernel_launch(void* const* d_in, const int* in_sizes, int n_in,
                              void* d_out, int out_size, void* d_ws, size_t ws_size,
                              hipStream_t stream) {
    const float* x         = (const float*)d_in[0];
    const float* cv0_off_w = (const float*)d_in[1];
    const float* cv0_off_b = (const float*)d_in[2];
    const float* cv0_w     = (const float*)d_in[3];
    const float* cvs_off_w = (const float*)d_in[4];
    const float* cvs_off_b = (const float*)d_in[5];
    const float* cvs_w     = (const float*)d_in[6];
    const float* c0_off_w  = (const float*)d_in[7];
    const float* c0_off_b  = (const float*)d_in[8];
    const float* c0_w      = (const float*)d_in[9];
    const float* cs_off_w  = (const float*)d_in[10];
    const float* cs_off_b  = (const float*)d_in[11];
    const float* cs_w      = (const float*)d_in[12];
    const float* conv1_w   = (const float*)d_in[13];
    const float* conv1_b   = (const float*)d_in[14];
    const float* conv2_w   = (const float*)d_in[15];
    const float* conv2_b   = (const float*)d_in[16];
    float* out = (float*)d_out;
    (void)d_ws; (void)ws_size;

    // Primary: cooperative launch (runtime guarantees 768-block co-residency
    // and grid.sync coherence; errors cleanly if unsupported).
    void* args[] = {
        (void*)&x,
        (void*)&cv0_off_w, (void*)&c0_off_w, (void*)&cvs_off_w, (void*)&cs_off_w,
        (void*)&cv0_w, (void*)&c0_w, (void*)&cvs_w, (void*)&cs_w,
        (void*)&cv0_off_b, (void*)&c0_off_b, (void*)&cvs_off_b, (void*)&cs_off_b,
        (void*)&conv1_w, (void*)&conv1_b, (void*)&conv2_w, (void*)&conv2_b,
        (void*)&out};
    hipError_t e = hipLaunchCooperativeKernel((const void*)mega_kernel,
                                              dim3(NBLK), dim3(256),
                                              args, 25088u, stream);
    if (e == hipSuccess) return;

    // Fallback: verified R7 six-kernel pipeline (final_kernel grid FIXED).
    prep_split_kernel<<<dim3(1359), 256, 0, stream>>>(
        x, cv0_off_w, c0_off_w, cvs_off_w, cs_off_w, cv0_w, c0_w, cvs_w, cs_w);
    conv_s1_kernel<<<dim3(384), 256, 19584, stream>>>(cv0_off_b, c0_off_b);
    sample_kernel<3, 5, 1><<<dim3(2048), 256, 0, stream>>>(
        XA_F32, OFF_A, DW_A1, A1_F32, A1_HI, A1_LO, 1, 1,
        XB_F32, OFF_B, DW_B1, B1_F32, B1_HI, B1_LO, 2, 1);
    conv_s2_kernel<<<dim3(512), 256, 23616, stream>>>(cvs_off_b, cs_off_b);
    sample_kernel<5, 7, 0><<<dim3(2048), 256, 0, stream>>>(
        A1_F32, OFF_A, DW_A2, A2_F32, 0, 0, 6, 3,
        B1_F32, OFF_B, DW_B2, B2_F32, 0, 0, 9, 3);
    final_kernel<<<dim3(512), 256, 0, stream>>>(
        x, conv1_w, conv1_b, conv2_w, conv2_b, out);
}